// Round 1
// baseline (666.561 us; speedup 1.0000x reference)
//
#include <hip/hip_runtime.h>
#include <math.h>

// Problem constants (from reference setup_inputs)
constexpr int Bn = 2;
constexpr int Sn = 2048;
constexpr int Vn = 32000;
constexpr int ROWS = Bn * (Sn - 1);  // 4094 shifted rows

#define SHOCK_THRESHOLD 5.0f
#define ALPHA 3.0f
#define EPS_C 1e-6f

// Combine two online-softmax partials (m, s, t):
//   s = sum exp(l - m), t = sum l*exp(l - m)
__device__ inline void combine(float& m, float& s, float& t,
                               float om, float os, float ot) {
    float nm = fmaxf(m, om);
    float sc1 = __expf(m - nm);
    float sc2 = __expf(om - nm);
    s = s * sc1 + os * sc2;
    t = t * sc1 + ot * sc2;
    m = nm;
}

__global__ __launch_bounds__(256) void reaft_row_kernel(
    const float* __restrict__ logits,
    const int* __restrict__ labels,
    const int* __restrict__ attn_mask,
    float* __restrict__ ws_w,   // per-row weighted loss
    float* __restrict__ ws_c) { // per-row valid flag (0/1)
    const int r = blockIdx.x;          // shifted-row index in [0, ROWS)
    const int b = r / (Sn - 1);
    const int s = r - b * (Sn - 1);

    const float* __restrict__ row = logits + (size_t)(b * Sn + s) * Vn;
    const int lab = labels[b * Sn + s + 1];
    const int msk = attn_mask[b * Sn + s + 1];

    // One streaming pass: online (max, sumexp, sum l*exp)
    const float4* __restrict__ row4 = (const float4*)row;
    float m = -INFINITY, sum = 0.0f, tsum = 0.0f;
    for (int i = threadIdx.x; i < Vn / 4; i += 256) {
        float4 x = row4[i];
        float mx = fmaxf(fmaxf(x.x, x.y), fmaxf(x.z, x.w));
        if (mx > m) {                 // rare after warm-up (~log n times)
            float sc = __expf(m - mx);  // exp(-inf)=0 on first hit: safe
            sum *= sc;
            tsum *= sc;
            m = mx;
        }
        float e0 = __expf(x.x - m);
        float e1 = __expf(x.y - m);
        float e2 = __expf(x.z - m);
        float e3 = __expf(x.w - m);
        sum  += (e0 + e1) + (e2 + e3);
        tsum += (x.x * e0 + x.y * e1) + (x.z * e2 + x.w * e3);
    }

    // Wave (64-lane) butterfly reduce of (m, sum, tsum)
    #pragma unroll
    for (int off = 32; off >= 1; off >>= 1) {
        float om = __shfl_xor(m, off);
        float os = __shfl_xor(sum, off);
        float ot = __shfl_xor(tsum, off);
        combine(m, sum, tsum, om, os, ot);
    }

    // Cross-wave (4 waves) via LDS
    __shared__ float lm[4], ls[4], lt[4];
    const int wave = threadIdx.x >> 6;
    const int lane = threadIdx.x & 63;
    if (lane == 0) { lm[wave] = m; ls[wave] = sum; lt[wave] = tsum; }
    __syncthreads();

    if (threadIdx.x == 0) {
        float M = lm[0], S = ls[0], T = lt[0];
        #pragma unroll
        for (int w = 1; w < 4; ++w) combine(M, S, T, lm[w], ls[w], lt[w]);

        const float lse = M + logf(S);
        const float mean_l = T / S;            // sum p*l
        const float entropy = lse - mean_l;    // = -sum p*log p

        const int safe_lab = (lab == -100) ? 0 : lab;
        const float label_logit = row[safe_lab];
        const float token_loss = lse - label_logit;   // -log_prob[label]

        const float norm_ent = entropy / logf((float)Vn);
        const float ratio = token_loss / (norm_ent + EPS_C);
        const float factor = fminf(ratio * (1.0f / SHOCK_THRESHOLD), 10.0f);
        const float weight = (ratio > SHOCK_THRESHOLD) ? (1.0f + ALPHA * factor)
                                                       : norm_ent;
        const bool valid = (lab != -100) && (msk != 0);
        ws_w[r] = valid ? token_loss * weight : 0.0f;
        ws_c[r] = valid ? 1.0f : 0.0f;
    }
}

__global__ __launch_bounds__(1024) void reaft_reduce_kernel(
    const float* __restrict__ ws_w,
    const float* __restrict__ ws_c,
    float* __restrict__ out) {
    float s = 0.0f, c = 0.0f;
    for (int i = threadIdx.x; i < ROWS; i += 1024) {
        s += ws_w[i];
        c += ws_c[i];
    }
    #pragma unroll
    for (int off = 32; off >= 1; off >>= 1) {
        s += __shfl_xor(s, off);
        c += __shfl_xor(c, off);
    }
    __shared__ float as_[16], ac_[16];
    const int wave = threadIdx.x >> 6;
    const int lane = threadIdx.x & 63;
    if (lane == 0) { as_[wave] = s; ac_[wave] = c; }
    __syncthreads();
    if (threadIdx.x == 0) {
        float S = 0.0f, C = 0.0f;
        #pragma unroll
        for (int w = 0; w < 16; ++w) { S += as_[w]; C += ac_[w]; }
        out[0] = S / fmaxf(C, 1.0f);
    }
}

extern "C" void kernel_launch(void* const* d_in, const int* in_sizes, int n_in,
                              void* d_out, int out_size, void* d_ws, size_t ws_size,
                              hipStream_t stream) {
    const float* logits = (const float*)d_in[0];
    const int* labels = (const int*)d_in[1];
    const int* attn = (const int*)d_in[2];
    float* out = (float*)d_out;

    float* ws_w = (float*)d_ws;          // ROWS floats
    float* ws_c = ws_w + ROWS;           // ROWS floats

    reaft_row_kernel<<<ROWS, 256, 0, stream>>>(logits, labels, attn, ws_w, ws_c);
    reaft_reduce_kernel<<<1, 1024, 0, stream>>>(ws_w, ws_c, out);
}

// Round 5
// 665.531 us; speedup vs baseline: 1.0015x; 1.0015x over previous
//
#include <hip/hip_runtime.h>
#include <math.h>

// Problem constants (from reference setup_inputs)
constexpr int Bn = 2;
constexpr int Sn = 2048;
constexpr int Vn = 32000;
constexpr int ROWS = Bn * (Sn - 1);  // 4094 shifted rows
constexpr int NV4 = Vn / 4;          // 8000 float4 per row

#define SHOCK_THRESHOLD 5.0f
#define ALPHA 3.0f
#define EPS_C 1e-6f

// Branch-free online-softmax accumulate of one float4.
// Invariant: s = sum exp(l - m), t = sum l*exp(l - m).
// m starts at -INF: __expf(-inf)=0 zeroes the (empty) history safely.
__device__ inline void acc4(float4 x, float& m, float& s, float& t) {
    float mx = fmaxf(fmaxf(x.x, x.y), fmaxf(x.z, x.w));
    float nm = fmaxf(m, mx);
    float sc = __expf(m - nm);          // == 1.0 when no new max
    float e0 = __expf(x.x - nm);
    float e1 = __expf(x.y - nm);
    float e2 = __expf(x.z - nm);
    float e3 = __expf(x.w - nm);
    s = s * sc + ((e0 + e1) + (e2 + e3));
    t = t * sc + ((x.x * e0 + x.y * e1) + (x.z * e2 + x.w * e3));
    m = nm;
}

// Combine two online partials.
__device__ inline void combine(float& m, float& s, float& t,
                               float om, float os, float ot) {
    float nm = fmaxf(m, om);
    float sc1 = __expf(m - nm);
    float sc2 = __expf(om - nm);
    s = s * sc1 + os * sc2;
    t = t * sc1 + ot * sc2;
    m = nm;
}

__global__ __launch_bounds__(256) void reaft_row_kernel(
    const float* __restrict__ logits,
    const int* __restrict__ labels,
    const int* __restrict__ attn_mask,
    float* __restrict__ ws_w,   // per-row weighted loss
    float* __restrict__ ws_c) { // per-row valid flag (0/1)
    const int r = blockIdx.x;          // shifted-row index in [0, ROWS)
    const int b = r / (Sn - 1);
    const int s = r - b * (Sn - 1);

    const float* __restrict__ row = logits + (size_t)(b * Sn + s) * Vn;
    const int lab = labels[b * Sn + s + 1];
    const int msk = attn_mask[b * Sn + s + 1];

    // Hoist the label-logit load: broadcast address, overlaps the stream.
    const int safe_lab = (lab == -100) ? 0 : lab;
    const float label_logit = row[safe_lab];

    // One streaming pass, 2x float4 unroll, two independent accumulators.
    const float4* __restrict__ row4 = (const float4*)row;
    float m0 = -INFINITY, s0 = 0.0f, t0 = 0.0f;
    float m1 = -INFINITY, s1 = 0.0f, t1 = 0.0f;
    int i = threadIdx.x;
    #pragma unroll 2
    for (; i + 256 < NV4; i += 512) {
        float4 a = row4[i];
        float4 c = row4[i + 256];
        acc4(a, m0, s0, t0);
        acc4(c, m1, s1, t1);
    }
    if (i < NV4) acc4(row4[i], m0, s0, t0);
    combine(m0, s0, t0, m1, s1, t1);

    // Wave (64-lane) butterfly reduce of (m, s, t)
    #pragma unroll
    for (int off = 32; off >= 1; off >>= 1) {
        float om = __shfl_xor(m0, off);
        float os = __shfl_xor(s0, off);
        float ot = __shfl_xor(t0, off);
        combine(m0, s0, t0, om, os, ot);
    }

    // Cross-wave (4 waves) via LDS
    __shared__ float lm[4], ls[4], lt[4];
    const int wave = threadIdx.x >> 6;
    const int lane = threadIdx.x & 63;
    if (lane == 0) { lm[wave] = m0; ls[wave] = s0; lt[wave] = t0; }
    __syncthreads();

    if (threadIdx.x == 0) {
        float M = lm[0], S = ls[0], T = lt[0];
        #pragma unroll
        for (int w = 1; w < 4; ++w) combine(M, S, T, lm[w], ls[w], lt[w]);

        const float lse = M + logf(S);
        const float mean_l = T / S;            // sum p*l
        const float entropy = lse - mean_l;    // = -sum p*log p

        const float token_loss = lse - label_logit;   // -log_prob[label]

        const float norm_ent = entropy / logf((float)Vn);
        const float ratio = token_loss / (norm_ent + EPS_C);
        const float factor = fminf(ratio * (1.0f / SHOCK_THRESHOLD), 10.0f);
        const float weight = (ratio > SHOCK_THRESHOLD) ? (1.0f + ALPHA * factor)
                                                       : norm_ent;
        const bool valid = (lab != -100) && (msk != 0);
        ws_w[r] = valid ? token_loss * weight : 0.0f;
        ws_c[r] = valid ? 1.0f : 0.0f;
    }
}

__global__ __launch_bounds__(1024) void reaft_reduce_kernel(
    const float* __restrict__ ws_w,
    const float* __restrict__ ws_c,
    float* __restrict__ out) {
    float s = 0.0f, c = 0.0f;
    for (int i = threadIdx.x; i < ROWS; i += 1024) {
        s += ws_w[i];
        c += ws_c[i];
    }
    #pragma unroll
    for (int off = 32; off >= 1; off >>= 1) {
        s += __shfl_xor(s, off);
        c += __shfl_xor(c, off);
    }
    __shared__ float as_[16], ac_[16];
    const int wave = threadIdx.x >> 6;
    const int lane = threadIdx.x & 63;
    if (lane == 0) { as_[wave] = s; ac_[wave] = c; }
    __syncthreads();
    if (threadIdx.x == 0) {
        float S = 0.0f, C = 0.0f;
        #pragma unroll
        for (int w = 0; w < 16; ++w) { S += as_[w]; C += ac_[w]; }
        out[0] = S / fmaxf(C, 1.0f);
    }
}

extern "C" void kernel_launch(void* const* d_in, const int* in_sizes, int n_in,
                              void* d_out, int out_size, void* d_ws, size_t ws_size,
                              hipStream_t stream) {
    const float* logits = (const float*)d_in[0];
    const int* labels = (const int*)d_in[1];
    const int* attn = (const int*)d_in[2];
    float* out = (float*)d_out;

    float* ws_w = (float*)d_ws;          // ROWS floats
    float* ws_c = ws_w + ROWS;           // ROWS floats

    reaft_row_kernel<<<ROWS, 256, 0, stream>>>(logits, labels, attn, ws_w, ws_c);
    reaft_reduce_kernel<<<1, 1024, 0, stream>>>(ws_w, ws_c, out);
}